// Round 8
// baseline (382.776 us; speedup 1.0000x reference)
//
#include <hip/hip_runtime.h>
#include <hip/hip_bf16.h>
#include <math.h>

#define NB 2
#define LL 64
#define NMESH 100000
#define HEADS_O 8
#define DHC 64
#define DMODEL 512
#define DINNER 1024
#define DSTATE 64
#define NH 16
#define CONVDIM 1152
#define DINPROJ 2208
#define DOUT 256
#define NCHUNK 6250   // 100000 / 16, exact

typedef __attribute__((ext_vector_type(8))) short short8v;   // 8 x bf16
typedef __attribute__((ext_vector_type(4))) float f32x4;

__device__ __forceinline__ unsigned short f2bf(float f) {
  union { float f; unsigned u; } v; v.f = f;
  unsigned u = v.u;
  u += 0x7FFFu + ((u >> 16) & 1u);
  return (unsigned short)(u >> 16);
}

__device__ __forceinline__ float dot4(float4 a, const float* b) {
  return a.x*b[0] + a.y*b[1] + a.z*b[2] + a.w*b[3];
}

__device__ __forceinline__ float silu(float s) { return s / (1.f + expf(-s)); }

#define GLDS(g, l) __builtin_amdgcn_global_load_lds( \
    (const __attribute__((address_space(1))) void*)(g), \
    (__attribute__((address_space(3))) void*)(l), 16, 0, 0)

// ---------------------------------------------------------------- K1: in_proj (weight-streaming)
__global__ void k_inproj(const float* __restrict__ st, const float* __restrict__ w,
                         float* __restrict__ zx) {
  int oc = blockIdx.x;             // 0..8 : o = oc*256 + t
  int blc = blockIdx.y;            // 0..15: bl = blc*8 + r
  int t = threadIdx.x;
  __shared__ float u[8][DMODEL];   // 16 KB
  for (int idx = t; idx < 8*DMODEL; idx += 256) {
    int r = idx >> 9, m = idx & 511;
    int bl = blc*8 + r; int b = bl >> 6, l = bl & 63;
    u[r][m] = st[((size_t)(b*HEADS_O + (m >> 6))*LL + l)*DHC + (m & 63)];
  }
  __syncthreads();
  int o = oc*256 + t;
  if (o < DINPROJ) {
    const float4* wr = (const float4*)(w + (size_t)o*DMODEL);
    float acc[8] = {0,0,0,0,0,0,0,0};
    for (int m4 = 0; m4 < DMODEL/4; ++m4) {
      float4 wv = wr[m4];
      #pragma unroll
      for (int r = 0; r < 8; ++r) acc[r] += dot4(wv, &u[r][m4*4]);
    }
    #pragma unroll
    for (int r = 0; r < 8; ++r)
      zx[(size_t)(blc*8 + r)*DINPROJ + o] = acc[r];
  }
}

// ---------------------------------------------------------------- K2: fused conv+silu AND dt softplus
__global__ void k_convdt(const float* __restrict__ zx, const float* __restrict__ cw,
                         const float* __restrict__ cb, const float* __restrict__ dtb,
                         float* __restrict__ conv_out, float* __restrict__ dtbuf) {
  if (blockIdx.x < 576) {
    int i = blockIdx.x*256 + threadIdx.x;           // < 147456
    int c = i % CONVDIM; int l = (i / CONVDIM) % LL; int b = i / (CONVDIM*LL);
    float s = cb[c];
    #pragma unroll
    for (int k = 0; k < 3; ++k) {
      int tt = l - 1 + k;
      if (tt >= 0 && tt < LL)
        s += cw[c*3 + k] * zx[(size_t)(b*LL + tt)*DINPROJ + DINNER + c];
    }
    conv_out[i] = silu(s);
  } else {
    int i = (blockIdx.x - 576)*256 + threadIdx.x;   // (s*64+l)*16+h, 4096 total
    if (i < 4*LL*NH) {
      int h = i & 15, l = (i >> 4) & 63, s = i >> 10;
      float v;
      if (s < 2)
        v = zx[(size_t)(s*LL + l)*DINPROJ + (DINNER + CONVDIM) + h];
      else
        v = zx[(size_t)((s-2)*LL + (63-l))*DINPROJ + (DINNER + CONVDIM) + 16 + h];
      v += dtb[h];
      dtbuf[i] = (v > 20.f) ? v : log1pf(expf(v));
    }
  }
}

// ---------------------------------------------------------------- K3: SSD scan (parallel form)
__global__ void k_scan(const float* __restrict__ conv_out, const float* __restrict__ dtbuf,
                       const float* __restrict__ A_log, float* __restrict__ ybuf) {
  int blk = blockIdx.x;
  int s = blk >> 4, hh = blk & 15;
  int b = s & 1;
  bool rev = (s >= 2);
  int t = threadIdx.x;
  int wv = t >> 6, lane = t & 63;
  __shared__ float Bs[64*68];
  __shared__ float Cs[64*68];
  __shared__ float Xs[64*64];
  __shared__ float dts[64];
  __shared__ float Dc[64];

  for (int id = t; id < 4096; id += 256) {
    int tt0 = id >> 6, n = id & 63;
    int tt = rev ? (63 - tt0) : tt0;
    size_t base = (size_t)(b*LL + tt) * CONVDIM;
    Xs[tt0*64 + n] = conv_out[base + hh*64 + n];
    Bs[tt0*68 + n] = conv_out[base + DINNER + n];
    Cs[tt0*68 + n] = conv_out[base + DINNER + DSTATE + n];
  }
  if (t < 64) dts[t] = dtbuf[(size_t)(s*LL + t)*NH + hh];
  __syncthreads();
  if (t < 64) {
    float v = dts[t];
    #pragma unroll
    for (int m = 1; m < 64; m <<= 1) {
      float o = __shfl_up(v, m, 64);
      if (lane >= m) v += o;
    }
    Dc[t] = v;
  }
  __syncthreads();
  float A = -expf(A_log[hh]);
  float g[16];
  #pragma unroll
  for (int i = 0; i < 16; ++i) {
    int tt = wv + 4*i;
    int ta = lane;
    float gv = 0.f;
    if (ta <= tt) {
      const float* Br = &Bs[ta*68];
      const float* Cr = &Cs[tt*68];
      float dot = 0.f;
      #pragma unroll
      for (int n4 = 0; n4 < 16; ++n4) {
        float4 bv = *(const float4*)&Br[n4*4];
        float4 cv = *(const float4*)&Cr[n4*4];
        dot += bv.x*cv.x + bv.y*cv.y + bv.z*cv.z + bv.w*cv.w;
      }
      gv = dot * expf(A * (Dc[tt] - Dc[ta])) * dts[ta];
    }
    g[i] = gv;
  }
  __syncthreads();
  #pragma unroll
  for (int i = 0; i < 16; ++i) Bs[(wv + 4*i)*64 + lane] = g[i];
  __syncthreads();
  for (int id = t; id < 4096; id += 256) {
    int tt = id >> 6, p = id & 63;
    float y = 0.f;
    for (int ta = 0; ta <= tt; ++ta) y += Bs[tt*64 + ta] * Xs[ta*64 + p];
    ybuf[(size_t)(s*LL + tt)*DINNER + hh*64 + p] = y;
  }
}

// ---------------------------------------------------------------- K4: combine + gate + RMS + out_proj + mfrag (fused)
__global__ void k_combo2(const float* __restrict__ conv_out, const float* __restrict__ zx,
                         const float* __restrict__ yb, const float* __restrict__ fcD,
                         const float* __restrict__ Dd, const float* __restrict__ nw,
                         const float* __restrict__ opw, const float* __restrict__ tow,
                         unsigned short* __restrict__ mfp) {
  int bl = blockIdx.x; int b = bl >> 6, l = bl & 63;
  int t = threadIdx.x;
  __shared__ float xog[DINNER];
  __shared__ float yrow[DINNER];
  __shared__ float ohs[DMODEL];
  __shared__ float diag[NH];
  __shared__ float wsum[4];
  #pragma unroll
  for (int i = 0; i < 4; ++i) {
    int c = t + 256*i;
    xog[c] = conv_out[(size_t)bl*CONVDIM + c];
  }
  __syncthreads();
  {
    int hh = t >> 4, j = t & 15;
    const float* fr = fcD + (size_t)hh*DINNER;
    float acc = 0.f;
    for (int k = 0; k < 64; ++k) acc += xog[j + 16*k] * fr[j + 16*k];
    #pragma unroll
    for (int m = 8; m >= 1; m >>= 1) acc += __shfl_xor(acc, m, 64);
    if (j == 0) diag[hh] = acc + Dd[hh];
  }
  __syncthreads();
  float ss = 0.f;
  float y2v[4];
  #pragma unroll
  for (int i = 0; i < 4; ++i) {
    int c = t + 256*i;
    float yf = (l == 0)  ? 0.f : yb[(size_t)(b*LL + l - 1)*DINNER + c];
    float yw = (l == 63) ? 0.f : yb[(size_t)((2+b)*LL + 62 - l)*DINNER + c];
    float y1 = yf + yw + xog[c]*diag[c >> 6];
    float z = zx[(size_t)bl*DINPROJ + c];
    float y2 = y1 * silu(z);
    y2v[i] = y2;
    ss += y2*y2;
  }
  #pragma unroll
  for (int m = 32; m >= 1; m >>= 1) ss += __shfl_xor(ss, m, 64);
  if ((t & 63) == 0) wsum[t >> 6] = ss;
  __syncthreads();
  float tot = wsum[0] + wsum[1] + wsum[2] + wsum[3];
  float scale = rsqrtf(tot * (1.f/1024.f) + 1e-5f);
  #pragma unroll
  for (int i = 0; i < 4; ++i) {
    int c = t + 256*i;
    yrow[c] = y2v[i] * scale * nw[c];
  }
  __syncthreads();
  // out_proj: 512 outs, 2 per thread
  #pragma unroll
  for (int oi = 0; oi < 2; ++oi) {
    int o = t + 256*oi;
    const float4* wr = (const float4*)(opw + (size_t)o*DINNER);
    float acc = 0.f;
    #pragma unroll 4
    for (int k4 = 0; k4 < DINNER/4; ++k4) acc += dot4(wr[k4], &yrow[k4*4]);
    ohs[o] = acc;
  }
  __syncthreads();
  // mfrag: M[b,h,g,d] = sum_c ohs[h*64+c]*tow[d,h*64+c]; this block owns g = l
  int g = l;
  int kkq = g >> 5;
  int lnhi = ((g & 31) >> 3) << 4;
  int j = g & 7;
  #pragma unroll
  for (int ii = 0; ii < 8; ++ii) {
    int idx = t + 256*ii;            // (h,d)
    int h = idx >> 8, d = idx & 255;
    const float4* wr = (const float4*)(tow + (size_t)d*DMODEL + h*64);
    const float* op = &ohs[h*64];
    float acc = 0.f;
    #pragma unroll
    for (int c4 = 0; c4 < 16; ++c4) acc += dot4(wr[c4], &op[c4*4]);
    int ln = (d & 15) | lnhi;
    mfp[((((size_t)(b*HEADS_O + h)*2 + kkq)*16 + (d >> 4))*64 + ln)*8 + j] = f2bf(acc);
  }
}

// ---------------------------------------------------------------- K5: streaming GEMM, GLDS A-ring in LDS, counted vmcnt
// out[b,n,d] = sum_{h,g} W[b,h,n,g]*M[b,h,g,d] + tob[d]
// 512 blocks x 512 thr (8 waves), 128 KB LDS -> 1 block/CU.
// Block = (rg 0..63, b, ch 0..3) with XCD-twin decode (round-7, verified:
// FETCH ~213MB = W read ~once from HBM). B panel 64 cols x K=512 bf16 in
// 64 KB LDS, staged once (single barrier). Each wave streams 16-row chunks
// c = rg + 64*(wv + 8i); per (h,kk) step its A fragment group (2 KB) is
// staged into a PRIVATE per-wave 4-slot LDS ring by 2 global_load_lds,
// issued 3 steps ahead; s_waitcnt vmcnt(4/20) hand-counted so 3 groups
// (6 KB/wave, 48 KB/CU) are ALWAYS in flight; no barriers, no VGPR ring.
__global__ __launch_bounds__(512, 1) void k_out_gemm(const float* __restrict__ W,
                                                     const unsigned short* __restrict__ mf,
                                                     const float* __restrict__ tob,
                                                     float* __restrict__ out) {
  int bx = blockIdx.x;
  int x  = bx & 7;                  // XCD (blockIdx round-robins XCDs)
  int s  = bx >> 3;                 // within-XCD slot 0..63
  int ch = s & 3;                   // col quarter (fastest -> twins adjacent)
  int b  = (s >> 2) & 1;
  int rg = x*8 + (s >> 3);          // 0..63
  int tid = threadIdx.x;
  int wv = tid >> 6, lane = tid & 63;
  int r16 = lane & 15, kg = lane >> 4;

  __shared__ __align__(16) unsigned short lsB[16*4*64*8];  // [ks][ctl][ln][8] = 64 KB
  __shared__ __align__(16) float lsA[8][4][512];           // per-wave 4-slot ring, 64 KB

  // ---- stage B quarter-panel once via registers
  {
    const unsigned short* mfb = mf + (size_t)b*(16*16*512);
    uint4 tmp[8];
    #pragma unroll
    for (int sw = 0; sw < 8; ++sw) {
      int i16 = sw*512 + tid;                 // 0..4095 16B-units
      int ks = i16 >> 8, rem = i16 & 255;
      int ctl = rem >> 6, ln = rem & 63;
      tmp[sw] = *(const uint4*)(mfb + ((size_t)(ks*16 + ch*4 + ctl)*64 + ln)*8);
    }
    #pragma unroll
    for (int sw = 0; sw < 8; ++sw) {
      int i16 = sw*512 + tid;
      *(uint4*)((unsigned short*)lsB + (size_t)i16*8) = tmp[sw];
    }
  }
  __syncthreads();                            // the only barrier

  int colg0 = ch*64 + r16;
  const size_t hst = (size_t)NMESH*64;        // W h-stride in floats
  const float* Wb = W + (size_t)b*HEADS_O*hst;

  int c = rg + 64*wv;                         // first chunk (< 512 <= NCHUNK)
  // per-lane A source offset for chunk cc, step (h,kk):
  //   Wb + h*hst + (cc*16 + r16)*64 + kk*32 + kg*8   (floats); sweep1 = +4
  long off_c = ((long)c*16 + r16)*64 + kg*8;

  // prologue: issue groups for steps 0,1,2 of first chunk into slots 0,1,2
  #pragma unroll
  for (int k = 0; k < 3; ++k) {
    const int h = k >> 1, kk = k & 1;
    const float* src = Wb + (size_t)h*hst + off_c + kk*32;
    GLDS(src,     &lsA[wv][k][lane*4]);
    GLDS(src + 4, &lsA[wv][k][256 + lane*4]);
  }
  asm volatile("s_waitcnt vmcnt(0)" ::: "memory");
  __builtin_amdgcn_sched_barrier(0);

  while (c < NCHUNK) {
    int cadv = c + 512;                       // 8 waves * 64 rowgroups
    int cpre = (cadv < NCHUNK) ? cadv : c;    // prefetch target (clamped)
    long off_n = ((long)cpre*16 + r16)*64 + kg*8;

    f32x4 acc[4];
    #pragma unroll
    for (int ct = 0; ct < 4; ++ct) acc[ct] = (f32x4){0.f,0.f,0.f,0.f};

    #pragma unroll
    for (int k = 0; k < 16; ++k) {
      // wait: group k landed. After a chunk's 16 stores, steps 0..2 must
      // allow 16 stores + 4 newer GLDS outstanding -> vmcnt(20); else 4.
      if (k < 3) { asm volatile("s_waitcnt vmcnt(20)" ::: "memory"); }
      else       { asm volatile("s_waitcnt vmcnt(4)"  ::: "memory"); }
      // read A fragment from ring slot k%4 (identity layout: own lane's 32B)
      const float* as = &lsA[wv][k & 3][0];
      float4 a0 = *(const float4*)(as + lane*4);
      float4 a1 = *(const float4*)(as + 256 + lane*4);
      // read B fragments (4 ct tiles) for k-slice ks = k
      const unsigned short* lb = (const unsigned short*)lsB + ((size_t)k*4*64 + lane)*8;
      short8v bf0 = *(const short8v*)(lb);
      short8v bf1 = *(const short8v*)(lb + 512);
      short8v bf2 = *(const short8v*)(lb + 1024);
      short8v bf3 = *(const short8v*)(lb + 1536);
      asm volatile("s_waitcnt lgkmcnt(0)" ::: "memory");
      __builtin_amdgcn_sched_barrier(0);
      // issue group k+3 into slot (k+3)%4 (that slot was consumed at step k-1)
      {
        const int kg3 = k + 3;
        const int hh2 = (kg3 < 16) ? (kg3 >> 1) : ((kg3 - 16) >> 1);
        const int kk2 = (kg3 < 16) ? (kg3 & 1)  : ((kg3 - 16) & 1);
        const long offX = (kg3 < 16) ? off_c : off_n;
        const float* src = Wb + (size_t)hh2*hst + offX + kk2*32;
        GLDS(src,     &lsA[wv][kg3 & 3][lane*4]);
        GLDS(src + 4, &lsA[wv][kg3 & 3][256 + lane*4]);
      }
      // convert + MFMA
      short8v af;
      af[0] = (short)f2bf(a0.x); af[1] = (short)f2bf(a0.y);
      af[2] = (short)f2bf(a0.z); af[3] = (short)f2bf(a0.w);
      af[4] = (short)f2bf(a1.x); af[5] = (short)f2bf(a1.y);
      af[6] = (short)f2bf(a1.z); af[7] = (short)f2bf(a1.w);
      acc[0] = __builtin_amdgcn_mfma_f32_16x16x32_bf16(af, bf0, acc[0], 0, 0, 0);
      acc[1] = __builtin_amdgcn_mfma_f32_16x16x32_bf16(af, bf1, acc[1], 0, 0, 0);
      acc[2] = __builtin_amdgcn_mfma_f32_16x16x32_bf16(af, bf2, acc[2], 0, 0, 0);
      acc[3] = __builtin_amdgcn_mfma_f32_16x16x32_bf16(af, bf3, acc[3], 0, 0, 0);
    }
    // pin stores AFTER the cross-chunk GLDS issues (vmcnt accounting)
    asm volatile("" ::: "memory");
    // store: C layout col=lane&15, row=(lane>>4)*4+r
    int rb = c*16 + kg*4;
    #pragma unroll
    for (int ct = 0; ct < 4; ++ct) {
      int colg = colg0 + ct*16;
      float bias = tob[colg];
      #pragma unroll
      for (int r = 0; r < 4; ++r)
        out[((size_t)b*NMESH + rb + r)*DOUT + colg] = acc[ct][r] + bias;
    }
    asm volatile("" ::: "memory");
    c = cadv;
    off_c = off_n;
  }
}

// ----------------------------------------------------------------
extern "C" void kernel_launch(void* const* d_in, const int* in_sizes, int n_in,
                              void* d_out, int out_size, void* d_ws, size_t ws_size,
                              hipStream_t stream) {
  (void)in_sizes; (void)n_in; (void)out_size; (void)ws_size;
  const float* st   = (const float*)d_in[0];
  const float* sw   = (const float*)d_in[1];
  const float* ipw  = (const float*)d_in[2];
  const float* cw   = (const float*)d_in[3];
  const float* cb   = (const float*)d_in[4];
  const float* dtb  = (const float*)d_in[5];
  const float* alog = (const float*)d_in[6];
  const float* fcD  = (const float*)d_in[7];
  const float* Dd   = (const float*)d_in[8];
  const float* nw   = (const float*)d_in[9];
  const float* opw  = (const float*)d_in[10];
  const float* tow  = (const float*)d_in[11];
  const float* tob  = (const float*)d_in[12];
  float* out = (float*)d_out;
  unsigned char* ws = (unsigned char*)d_ws;

  float* zx   = (float*)(ws + 0);            // 2*64*2208*4   = 1130496
  float* conv = (float*)(ws + 1130496);      // 2*64*1152*4   = 589824
  float* dtp  = (float*)(ws + 1720320);      // 4*64*16*4     = 16384
  float* yb   = (float*)(ws + 1736704);      // 4*64*1024*4   = 1048576
  unsigned short* mfr = (unsigned short*)(ws + 2785280);  // 524288

  k_inproj  <<<dim3(9, 16), 256, 0, stream>>>(st, ipw, zx);
  k_convdt  <<<592, 256, 0, stream>>>(zx, cw, cb, dtb, conv, dtp);
  k_scan    <<<64,  256, 0, stream>>>(conv, dtp, alog, yb);
  k_combo2  <<<128, 256, 0, stream>>>(conv, zx, yb, fcD, Dd, nw, opw, tow, mfr);
  k_out_gemm<<<512, 512, 0, stream>>>(sw, mfr, tob, out);
}

// Round 9
// 295.125 us; speedup vs baseline: 1.2970x; 1.2970x over previous
//
#include <hip/hip_runtime.h>
#include <hip/hip_bf16.h>
#include <math.h>

#define NB 2
#define LL 64
#define NMESH 100000
#define HEADS_O 8
#define DHC 64
#define DMODEL 512
#define DINNER 1024
#define DSTATE 64
#define NH 16
#define CONVDIM 1152
#define DINPROJ 2208
#define DOUT 256
#define NCHUNK 6250   // 100000 / 16, exact

typedef __attribute__((ext_vector_type(8))) short short8v;   // 8 x bf16
typedef __attribute__((ext_vector_type(4))) float f32x4;

__device__ __forceinline__ unsigned short f2bf(float f) {
  union { float f; unsigned u; } v; v.f = f;
  unsigned u = v.u;
  u += 0x7FFFu + ((u >> 16) & 1u);
  return (unsigned short)(u >> 16);
}

__device__ __forceinline__ float dot4(float4 a, const float* b) {
  return a.x*b[0] + a.y*b[1] + a.z*b[2] + a.w*b[3];
}

__device__ __forceinline__ float silu(float s) { return s / (1.f + expf(-s)); }

#define GLDS(g, l) __builtin_amdgcn_global_load_lds( \
    (const __attribute__((address_space(1))) void*)(g), \
    (__attribute__((address_space(3))) void*)(l), 16, 0, 0)

// ---------------------------------------------------------------- K1: in_proj (weight-streaming)
__global__ void k_inproj(const float* __restrict__ st, const float* __restrict__ w,
                         float* __restrict__ zx) {
  int oc = blockIdx.x;             // 0..8 : o = oc*256 + t
  int blc = blockIdx.y;            // 0..15: bl = blc*8 + r
  int t = threadIdx.x;
  __shared__ float u[8][DMODEL];   // 16 KB
  for (int idx = t; idx < 8*DMODEL; idx += 256) {
    int r = idx >> 9, m = idx & 511;
    int bl = blc*8 + r; int b = bl >> 6, l = bl & 63;
    u[r][m] = st[((size_t)(b*HEADS_O + (m >> 6))*LL + l)*DHC + (m & 63)];
  }
  __syncthreads();
  int o = oc*256 + t;
  if (o < DINPROJ) {
    const float4* wr = (const float4*)(w + (size_t)o*DMODEL);
    float acc[8] = {0,0,0,0,0,0,0,0};
    for (int m4 = 0; m4 < DMODEL/4; ++m4) {
      float4 wv = wr[m4];
      #pragma unroll
      for (int r = 0; r < 8; ++r) acc[r] += dot4(wv, &u[r][m4*4]);
    }
    #pragma unroll
    for (int r = 0; r < 8; ++r)
      zx[(size_t)(blc*8 + r)*DINPROJ + o] = acc[r];
  }
}

// ---------------------------------------------------------------- K2: fused conv+silu AND dt softplus
__global__ void k_convdt(const float* __restrict__ zx, const float* __restrict__ cw,
                         const float* __restrict__ cb, const float* __restrict__ dtb,
                         float* __restrict__ conv_out, float* __restrict__ dtbuf) {
  if (blockIdx.x < 576) {
    int i = blockIdx.x*256 + threadIdx.x;           // < 147456
    int c = i % CONVDIM; int l = (i / CONVDIM) % LL; int b = i / (CONVDIM*LL);
    float s = cb[c];
    #pragma unroll
    for (int k = 0; k < 3; ++k) {
      int tt = l - 1 + k;
      if (tt >= 0 && tt < LL)
        s += cw[c*3 + k] * zx[(size_t)(b*LL + tt)*DINPROJ + DINNER + c];
    }
    conv_out[i] = silu(s);
  } else {
    int i = (blockIdx.x - 576)*256 + threadIdx.x;   // (s*64+l)*16+h, 4096 total
    if (i < 4*LL*NH) {
      int h = i & 15, l = (i >> 4) & 63, s = i >> 10;
      float v;
      if (s < 2)
        v = zx[(size_t)(s*LL + l)*DINPROJ + (DINNER + CONVDIM) + h];
      else
        v = zx[(size_t)((s-2)*LL + (63-l))*DINPROJ + (DINNER + CONVDIM) + 16 + h];
      v += dtb[h];
      dtbuf[i] = (v > 20.f) ? v : log1pf(expf(v));
    }
  }
}

// ---------------------------------------------------------------- K3: SSD scan (parallel form)
__global__ void k_scan(const float* __restrict__ conv_out, const float* __restrict__ dtbuf,
                       const float* __restrict__ A_log, float* __restrict__ ybuf) {
  int blk = blockIdx.x;
  int s = blk >> 4, hh = blk & 15;
  int b = s & 1;
  bool rev = (s >= 2);
  int t = threadIdx.x;
  int wv = t >> 6, lane = t & 63;
  __shared__ float Bs[64*68];
  __shared__ float Cs[64*68];
  __shared__ float Xs[64*64];
  __shared__ float dts[64];
  __shared__ float Dc[64];

  for (int id = t; id < 4096; id += 256) {
    int tt0 = id >> 6, n = id & 63;
    int tt = rev ? (63 - tt0) : tt0;
    size_t base = (size_t)(b*LL + tt) * CONVDIM;
    Xs[tt0*64 + n] = conv_out[base + hh*64 + n];
    Bs[tt0*68 + n] = conv_out[base + DINNER + n];
    Cs[tt0*68 + n] = conv_out[base + DINNER + DSTATE + n];
  }
  if (t < 64) dts[t] = dtbuf[(size_t)(s*LL + t)*NH + hh];
  __syncthreads();
  if (t < 64) {
    float v = dts[t];
    #pragma unroll
    for (int m = 1; m < 64; m <<= 1) {
      float o = __shfl_up(v, m, 64);
      if (lane >= m) v += o;
    }
    Dc[t] = v;
  }
  __syncthreads();
  float A = -expf(A_log[hh]);
  float g[16];
  #pragma unroll
  for (int i = 0; i < 16; ++i) {
    int tt = wv + 4*i;
    int ta = lane;
    float gv = 0.f;
    if (ta <= tt) {
      const float* Br = &Bs[ta*68];
      const float* Cr = &Cs[tt*68];
      float dot = 0.f;
      #pragma unroll
      for (int n4 = 0; n4 < 16; ++n4) {
        float4 bv = *(const float4*)&Br[n4*4];
        float4 cv = *(const float4*)&Cr[n4*4];
        dot += bv.x*cv.x + bv.y*cv.y + bv.z*cv.z + bv.w*cv.w;
      }
      gv = dot * expf(A * (Dc[tt] - Dc[ta])) * dts[ta];
    }
    g[i] = gv;
  }
  __syncthreads();
  #pragma unroll
  for (int i = 0; i < 16; ++i) Bs[(wv + 4*i)*64 + lane] = g[i];
  __syncthreads();
  for (int id = t; id < 4096; id += 256) {
    int tt = id >> 6, p = id & 63;
    float y = 0.f;
    for (int ta = 0; ta <= tt; ++ta) y += Bs[tt*64 + ta] * Xs[ta*64 + p];
    ybuf[(size_t)(s*LL + tt)*DINNER + hh*64 + p] = y;
  }
}

// ---------------------------------------------------------------- K4: combine + gate + RMSnorm -> ynorm
__global__ void k_norm(const float* __restrict__ conv_out, const float* __restrict__ zx,
                       const float* __restrict__ yb, const float* __restrict__ fcD,
                       const float* __restrict__ Dd, const float* __restrict__ nw,
                       float* __restrict__ ynorm) {
  int bl = blockIdx.x; int b = bl >> 6, l = bl & 63;
  int t = threadIdx.x;
  __shared__ float xog[DINNER];
  __shared__ float diag[NH];
  __shared__ float wsum[4];
  size_t base = (size_t)bl * CONVDIM;
  for (int c = t; c < DINNER; c += 256) xog[c] = conv_out[base + c];
  __syncthreads();
  {
    int hh = t >> 4, j = t & 15;
    const float* fr = fcD + (size_t)hh*DINNER;
    float acc = 0.f;
    for (int k = 0; k < 64; ++k) acc += xog[j + 16*k] * fr[j + 16*k];
    #pragma unroll
    for (int m = 8; m >= 1; m >>= 1) acc += __shfl_xor(acc, m, 64);
    if (j == 0) diag[hh] = acc + Dd[hh];
  }
  __syncthreads();
  float ss = 0.f;
  float y2v[4];
  #pragma unroll
  for (int i = 0; i < 4; ++i) {
    int c = t + 256*i;
    float yf = (l == 0)  ? 0.f : yb[(size_t)(b*LL + l - 1)*DINNER + c];
    float yw = (l == 63) ? 0.f : yb[(size_t)((2+b)*LL + 62 - l)*DINNER + c];
    float y1 = yf + yw + xog[c]*diag[c >> 6];
    float z = zx[(size_t)bl*DINPROJ + c];
    float y2 = y1 * silu(z);
    y2v[i] = y2;
    ss += y2*y2;
  }
  #pragma unroll
  for (int m = 32; m >= 1; m >>= 1) ss += __shfl_xor(ss, m, 64);
  if ((t & 63) == 0) wsum[t >> 6] = ss;
  __syncthreads();
  float tot = wsum[0] + wsum[1] + wsum[2] + wsum[3];
  float scale = rsqrtf(tot * (1.f/1024.f) + 1e-5f);
  #pragma unroll
  for (int i = 0; i < 4; ++i) {
    int c = t + 256*i;
    ynorm[(size_t)bl*DINNER + c] = y2v[i] * scale * nw[c];
  }
}

// ---------------------------------------------------------------- K5: out_proj (weight-streaming)
__global__ void k_oproj(const float* __restrict__ ynorm, const float* __restrict__ opw,
                        float* __restrict__ oh) {
  int oc = blockIdx.x;            // 0..1 : o = oc*256 + t
  int blc = blockIdx.y;           // 0..31: bl = blc*4 + r
  int t = threadIdx.x;
  __shared__ float yr[4][DINNER]; // 16 KB
  for (int idx = t; idx < 4*DINNER; idx += 256) {
    int r = idx >> 10, k = idx & 1023;
    yr[r][k] = ynorm[(size_t)(blc*4 + r)*DINNER + k];
  }
  __syncthreads();
  int o = oc*256 + t;
  const float4* wr = (const float4*)(opw + (size_t)o*DINNER);
  float acc[4] = {0,0,0,0};
  for (int k4 = 0; k4 < DINNER/4; ++k4) {
    float4 wv = wr[k4];
    #pragma unroll
    for (int r = 0; r < 4; ++r) acc[r] += dot4(wv, &yr[r][k4*4]);
  }
  #pragma unroll
  for (int r = 0; r < 4; ++r)
    oh[(size_t)(blc*4 + r)*DMODEL + o] = acc[r];
}

// ---------------------------------------------------------------- K6: build M in B-fragment order (bf16)
__global__ void k_mfrag(const float* __restrict__ oh, const float* __restrict__ tow,
                        unsigned short* __restrict__ mfp) {
  int bgc = blockIdx.x;            // 0..15, bg = bgc*8 + r
  int dc  = blockIdx.y;            // 0..3 : d = dc*64 + dl
  int t = threadIdx.x;
  __shared__ float orow[8][DMODEL]; // 16 KB
  for (int idx = t; idx < 8*DMODEL; idx += 256) {
    int r = idx >> 9, m = idx & 511;
    orow[r][m] = oh[(size_t)(bgc*8 + r)*DMODEL + m];
  }
  __syncthreads();
  #pragma unroll
  for (int ii = 0; ii < 2; ++ii) {
    int idx = t + 256*ii;          // 0..511 -> (h, dl)
    int h = idx >> 6, dl = idx & 63;
    int d = dc*64 + dl;
    const float4* wr = (const float4*)(tow + (size_t)d*DMODEL + h*64);
    float acc[8] = {0,0,0,0,0,0,0,0};
    #pragma unroll
    for (int c4 = 0; c4 < 16; ++c4) {
      float4 wv = wr[c4];
      #pragma unroll
      for (int r = 0; r < 8; ++r) acc[r] += dot4(wv, &orow[r][h*64 + c4*4]);
    }
    #pragma unroll
    for (int r = 0; r < 8; ++r) {
      int bg = bgc*8 + r; int b = bg >> 6, g = bg & 63;
      int kk = g >> 5;
      int ln = (d & 15) | (((g & 31) >> 3) << 4);
      int j = g & 7;
      mfp[((((size_t)(b*HEADS_O + h)*2 + kk)*16 + (d >> 4))*64 + ln)*8 + j] = f2bf(acc[r]);
    }
  }
}

// ---------------------------------------------------------------- K7: amplification-1x GEMM
// out[b,n,d] = sum_{h,g} W[b,h,n,g]*M[b,h,g,d] + tob[d]
// 256 blocks x 512 thr (8 waves), 1 block/CU. Block owns b = bx>>7 and
// chunks c = (bx&127) + 128k. Per chunk (16 rows): full K=512 of A (32 KB)
// is GLDS-staged ONCE into a double-buffered LDS tile (wave w stages k-steps
// 2w,2w+1) and consumed by ALL waves; B (256 cols x K=512 bf16) lives in
// REGISTERS: wave w holds ct tiles {2w,2w+1} = 128 VGPRs, loaded once.
// => W crosses the fabric exactly once (410 MB) + stores (205 MB); no
// re-reads, no col-split amplification. Counted vmcnt(8): next-chunk GLDS
// stays in flight across the per-chunk barrier; stores never drained.
__global__ __launch_bounds__(512, 2) void k_out_gemm(const float* __restrict__ W,
                                                     const unsigned short* __restrict__ mf,
                                                     const float* __restrict__ tob,
                                                     float* __restrict__ out) {
  int bx = blockIdx.x;
  int b    = bx >> 7;
  int base = bx & 127;
  int tid = threadIdx.x;
  int wv = tid >> 6, lane = tid & 63;
  int r16 = lane & 15, kg = lane >> 4;

  __shared__ __align__(16) float lsA[2][16][512];   // [buf][ks][8 floats/lane] = 64 KB

  // ---- B fragments into registers: wave wv owns ct = 2wv, 2wv+1
  short8v B0[16], B1[16];
  {
    const unsigned short* mfb = mf + (size_t)b*(16*16*512) + lane*8;
    #pragma unroll
    for (int ks = 0; ks < 16; ++ks) {
      B0[ks] = *(const short8v*)(mfb + ((size_t)ks*16 + 2*wv    )*512);
      B1[ks] = *(const short8v*)(mfb + ((size_t)ks*16 + 2*wv + 1)*512);
    }
  }
  float bias0 = tob[wv*32 + r16];
  float bias1 = tob[wv*32 + 16 + r16];

  // ---- stage macro: wave wv stages k-steps 2wv, 2wv+1 of chunk cc into buf p
  #define STAGE(cc, p) do { \
    _Pragma("unroll") \
    for (int q = 0; q < 2; ++q) { \
      int ksl = 2*wv + q; \
      int h = ksl >> 1, kk = ksl & 1; \
      const float* src = W + ((size_t)(b*HEADS_O + h)*NMESH + (size_t)(cc)*16 + r16)*64 \
                           + kk*32 + kg*8; \
      GLDS(src,     &lsA[p][ksl][0]);   \
      GLDS(src + 4, &lsA[p][ksl][256]); \
    } \
  } while (0)

  int c = base;
  int p = 0;
  STAGE(c, 0);
  asm volatile("s_waitcnt vmcnt(0)" ::: "memory");
  __builtin_amdgcn_s_barrier();
  __builtin_amdgcn_sched_barrier(0);

  while (true) {
    int cn = c + 128;
    bool more = (cn < NCHUNK);
    if (more) STAGE(cn, p ^ 1);          // 4 GLDS, in flight across compute

    f32x4 acc0 = (f32x4){0.f,0.f,0.f,0.f};
    f32x4 acc1 = (f32x4){0.f,0.f,0.f,0.f};
    #pragma unroll
    for (int ks = 0; ks < 16; ++ks) {
      const float* as = &lsA[p][ks][0];
      float4 a0 = *(const float4*)(as + lane*4);
      float4 a1 = *(const float4*)(as + 256 + lane*4);
      short8v af;
      af[0] = (short)f2bf(a0.x); af[1] = (short)f2bf(a0.y);
      af[2] = (short)f2bf(a0.z); af[3] = (short)f2bf(a0.w);
      af[4] = (short)f2bf(a1.x); af[5] = (short)f2bf(a1.y);
      af[6] = (short)f2bf(a1.z); af[7] = (short)f2bf(a1.w);
      acc0 = __builtin_amdgcn_mfma_f32_16x16x32_bf16(af, B0[ks], acc0, 0, 0, 0);
      acc1 = __builtin_amdgcn_mfma_f32_16x16x32_bf16(af, B1[ks], acc1, 0, 0, 0);
    }

    // store 16x16 tiles: col=lane&15, row=kg*4+r
    int rb = c*16 + kg*4;
    int cg = wv*32 + r16;
    #pragma unroll
    for (int r = 0; r < 4; ++r) {
      out[((size_t)b*NMESH + rb + r)*DOUT + cg]      = acc0[r] + bias0;
      out[((size_t)b*NMESH + rb + r)*DOUT + cg + 16] = acc1[r] + bias1;
    }

    if (!more) break;
    // 8 newest vmem = the 8 stores; everything older (incl. 4 GLDS) done.
    asm volatile("s_waitcnt vmcnt(8) lgkmcnt(0)" ::: "memory");
    __builtin_amdgcn_s_barrier();
    __builtin_amdgcn_sched_barrier(0);
    p ^= 1;
    c = cn;
  }
  #undef STAGE
}

// ----------------------------------------------------------------
extern "C" void kernel_launch(void* const* d_in, const int* in_sizes, int n_in,
                              void* d_out, int out_size, void* d_ws, size_t ws_size,
                              hipStream_t stream) {
  (void)in_sizes; (void)n_in; (void)out_size; (void)ws_size;
  const float* st   = (const float*)d_in[0];
  const float* sw   = (const float*)d_in[1];
  const float* ipw  = (const float*)d_in[2];
  const float* cw   = (const float*)d_in[3];
  const float* cb   = (const float*)d_in[4];
  const float* dtb  = (const float*)d_in[5];
  const float* alog = (const float*)d_in[6];
  const float* fcD  = (const float*)d_in[7];
  const float* Dd   = (const float*)d_in[8];
  const float* nw   = (const float*)d_in[9];
  const float* opw  = (const float*)d_in[10];
  const float* tow  = (const float*)d_in[11];
  const float* tob  = (const float*)d_in[12];
  float* out = (float*)d_out;
  unsigned char* ws = (unsigned char*)d_ws;

  float* zx   = (float*)(ws + 0);            // 2*64*2208*4 = 1130496
  float* conv = (float*)(ws + 1130496);      // 2*64*1152*4 = 589824
  float* dtp  = (float*)(ws + 1720320);      // 4*64*16*4   = 16384
  float* yb   = (float*)(ws + 1736704);      // 4*64*1024*4 = 1048576
  float* ynm  = (float*)(ws + 2785280);      // 2*64*1024*4 = 524288
  float* oh   = (float*)(ws + 3309568);      // 2*64*512*4  = 262144
  unsigned short* mfr = (unsigned short*)(ws + 3571712);  // 524288

  k_inproj  <<<dim3(9, 16), 256, 0, stream>>>(st, ipw, zx);
  k_convdt  <<<592, 256, 0, stream>>>(zx, cw, cb, dtb, conv, dtp);
  k_scan    <<<64,  256, 0, stream>>>(conv, dtp, alog, yb);
  k_norm    <<<128, 256, 0, stream>>>(conv, zx, yb, fcD, Dd, nw, ynm);
  k_oproj   <<<dim3(2, 32), 256, 0, stream>>>(ynm, opw, oh);
  k_mfrag   <<<dim3(16, 4), 256, 0, stream>>>(oh, tow, mfr);
  k_out_gemm<<<256, 512, 0, stream>>>(sw, mfr, tob, out);
}

// Round 10
// 241.892 us; speedup vs baseline: 1.5824x; 1.2201x over previous
//
#include <hip/hip_runtime.h>
#include <hip/hip_bf16.h>
#include <math.h>

#define NB 2
#define LL 64
#define NMESH 100000
#define HEADS_O 8
#define DHC 64
#define DMODEL 512
#define DINNER 1024
#define DSTATE 64
#define NH 16
#define CONVDIM 1152
#define DINPROJ 2208
#define DOUT 256
#define NCHUNK 6250   // 100000 / 16, exact

typedef __attribute__((ext_vector_type(8))) short short8v;   // 8 x bf16
typedef __attribute__((ext_vector_type(4))) float f32x4;

__device__ __forceinline__ unsigned short f2bf(float f) {
  union { float f; unsigned u; } v; v.f = f;
  unsigned u = v.u;
  u += 0x7FFFu + ((u >> 16) & 1u);
  return (unsigned short)(u >> 16);
}

__device__ __forceinline__ short8v pack_bf16(float4 lo, float4 hi) {
  short8v r;
  r[0] = (short)f2bf(lo.x); r[1] = (short)f2bf(lo.y);
  r[2] = (short)f2bf(lo.z); r[3] = (short)f2bf(lo.w);
  r[4] = (short)f2bf(hi.x); r[5] = (short)f2bf(hi.y);
  r[6] = (short)f2bf(hi.z); r[7] = (short)f2bf(hi.w);
  return r;
}

__device__ __forceinline__ float dot4(float4 a, const float* b) {
  return a.x*b[0] + a.y*b[1] + a.z*b[2] + a.w*b[3];
}

__device__ __forceinline__ float silu(float s) { return s / (1.f + expf(-s)); }

// ---------------------------------------------------------------- K1: in_proj (weight-streaming)
__global__ void k_inproj(const float* __restrict__ st, const float* __restrict__ w,
                         float* __restrict__ zx) {
  int oc = blockIdx.x;             // 0..8 : o = oc*256 + t
  int blc = blockIdx.y;            // 0..15: bl = blc*8 + r
  int t = threadIdx.x;
  __shared__ float u[8][DMODEL];   // 16 KB
  for (int idx = t; idx < 8*DMODEL; idx += 256) {
    int r = idx >> 9, m = idx & 511;
    int bl = blc*8 + r; int b = bl >> 6, l = bl & 63;
    u[r][m] = st[((size_t)(b*HEADS_O + (m >> 6))*LL + l)*DHC + (m & 63)];
  }
  __syncthreads();
  int o = oc*256 + t;
  if (o < DINPROJ) {
    const float4* wr = (const float4*)(w + (size_t)o*DMODEL);
    float acc[8] = {0,0,0,0,0,0,0,0};
    for (int m4 = 0; m4 < DMODEL/4; ++m4) {
      float4 wv = wr[m4];
      #pragma unroll
      for (int r = 0; r < 8; ++r) acc[r] += dot4(wv, &u[r][m4*4]);
    }
    #pragma unroll
    for (int r = 0; r < 8; ++r)
      zx[(size_t)(blc*8 + r)*DINPROJ + o] = acc[r];
  }
}

// ---------------------------------------------------------------- K2: fused conv+silu AND dt softplus
__global__ void k_convdt(const float* __restrict__ zx, const float* __restrict__ cw,
                         const float* __restrict__ cb, const float* __restrict__ dtb,
                         float* __restrict__ conv_out, float* __restrict__ dtbuf) {
  if (blockIdx.x < 576) {
    int i = blockIdx.x*256 + threadIdx.x;           // < 147456
    int c = i % CONVDIM; int l = (i / CONVDIM) % LL; int b = i / (CONVDIM*LL);
    float s = cb[c];
    #pragma unroll
    for (int k = 0; k < 3; ++k) {
      int tt = l - 1 + k;
      if (tt >= 0 && tt < LL)
        s += cw[c*3 + k] * zx[(size_t)(b*LL + tt)*DINPROJ + DINNER + c];
    }
    conv_out[i] = silu(s);
  } else {
    int i = (blockIdx.x - 576)*256 + threadIdx.x;   // (s*64+l)*16+h, 4096 total
    if (i < 4*LL*NH) {
      int h = i & 15, l = (i >> 4) & 63, s = i >> 10;
      float v;
      if (s < 2)
        v = zx[(size_t)(s*LL + l)*DINPROJ + (DINNER + CONVDIM) + h];
      else
        v = zx[(size_t)((s-2)*LL + (63-l))*DINPROJ + (DINNER + CONVDIM) + 16 + h];
      v += dtb[h];
      dtbuf[i] = (v > 20.f) ? v : log1pf(expf(v));
    }
  }
}

// ---------------------------------------------------------------- K3: SSD scan (parallel form)
__global__ void k_scan(const float* __restrict__ conv_out, const float* __restrict__ dtbuf,
                       const float* __restrict__ A_log, float* __restrict__ ybuf) {
  int blk = blockIdx.x;
  int s = blk >> 4, hh = blk & 15;
  int b = s & 1;
  bool rev = (s >= 2);
  int t = threadIdx.x;
  int wv = t >> 6, lane = t & 63;
  __shared__ float Bs[64*68];
  __shared__ float Cs[64*68];
  __shared__ float Xs[64*64];
  __shared__ float dts[64];
  __shared__ float Dc[64];

  for (int id = t; id < 4096; id += 256) {
    int tt0 = id >> 6, n = id & 63;
    int tt = rev ? (63 - tt0) : tt0;
    size_t base = (size_t)(b*LL + tt) * CONVDIM;
    Xs[tt0*64 + n] = conv_out[base + hh*64 + n];
    Bs[tt0*68 + n] = conv_out[base + DINNER + n];
    Cs[tt0*68 + n] = conv_out[base + DINNER + DSTATE + n];
  }
  if (t < 64) dts[t] = dtbuf[(size_t)(s*LL + t)*NH + hh];
  __syncthreads();
  if (t < 64) {
    float v = dts[t];
    #pragma unroll
    for (int m = 1; m < 64; m <<= 1) {
      float o = __shfl_up(v, m, 64);
      if (lane >= m) v += o;
    }
    Dc[t] = v;
  }
  __syncthreads();
  float A = -expf(A_log[hh]);
  float g[16];
  #pragma unroll
  for (int i = 0; i < 16; ++i) {
    int tt = wv + 4*i;
    int ta = lane;
    float gv = 0.f;
    if (ta <= tt) {
      const float* Br = &Bs[ta*68];
      const float* Cr = &Cs[tt*68];
      float dot = 0.f;
      #pragma unroll
      for (int n4 = 0; n4 < 16; ++n4) {
        float4 bv = *(const float4*)&Br[n4*4];
        float4 cv = *(const float4*)&Cr[n4*4];
        dot += bv.x*cv.x + bv.y*cv.y + bv.z*cv.z + bv.w*cv.w;
      }
      gv = dot * expf(A * (Dc[tt] - Dc[ta])) * dts[ta];
    }
    g[i] = gv;
  }
  __syncthreads();
  #pragma unroll
  for (int i = 0; i < 16; ++i) Bs[(wv + 4*i)*64 + lane] = g[i];
  __syncthreads();
  for (int id = t; id < 4096; id += 256) {
    int tt = id >> 6, p = id & 63;
    float y = 0.f;
    for (int ta = 0; ta <= tt; ++ta) y += Bs[tt*64 + ta] * Xs[ta*64 + p];
    ybuf[(size_t)(s*LL + tt)*DINNER + hh*64 + p] = y;
  }
}

// ---------------------------------------------------------------- K4: combine + gate + RMSnorm -> ynorm
__global__ void k_norm(const float* __restrict__ conv_out, const float* __restrict__ zx,
                       const float* __restrict__ yb, const float* __restrict__ fcD,
                       const float* __restrict__ Dd, const float* __restrict__ nw,
                       float* __restrict__ ynorm) {
  int bl = blockIdx.x; int b = bl >> 6, l = bl & 63;
  int t = threadIdx.x;
  __shared__ float xog[DINNER];
  __shared__ float diag[NH];
  __shared__ float wsum[4];
  size_t base = (size_t)bl * CONVDIM;
  for (int c = t; c < DINNER; c += 256) xog[c] = conv_out[base + c];
  __syncthreads();
  {
    int hh = t >> 4, j = t & 15;
    const float* fr = fcD + (size_t)hh*DINNER;
    float acc = 0.f;
    for (int k = 0; k < 64; ++k) acc += xog[j + 16*k] * fr[j + 16*k];
    #pragma unroll
    for (int m = 8; m >= 1; m >>= 1) acc += __shfl_xor(acc, m, 64);
    if (j == 0) diag[hh] = acc + Dd[hh];
  }
  __syncthreads();
  float ss = 0.f;
  float y2v[4];
  #pragma unroll
  for (int i = 0; i < 4; ++i) {
    int c = t + 256*i;
    float yf = (l == 0)  ? 0.f : yb[(size_t)(b*LL + l - 1)*DINNER + c];
    float yw = (l == 63) ? 0.f : yb[(size_t)((2+b)*LL + 62 - l)*DINNER + c];
    float y1 = yf + yw + xog[c]*diag[c >> 6];
    float z = zx[(size_t)bl*DINPROJ + c];
    float y2 = y1 * silu(z);
    y2v[i] = y2;
    ss += y2*y2;
  }
  #pragma unroll
  for (int m = 32; m >= 1; m >>= 1) ss += __shfl_xor(ss, m, 64);
  if ((t & 63) == 0) wsum[t >> 6] = ss;
  __syncthreads();
  float tot = wsum[0] + wsum[1] + wsum[2] + wsum[3];
  float scale = rsqrtf(tot * (1.f/1024.f) + 1e-5f);
  #pragma unroll
  for (int i = 0; i < 4; ++i) {
    int c = t + 256*i;
    ynorm[(size_t)bl*DINNER + c] = y2v[i] * scale * nw[c];
  }
}

// ---------------------------------------------------------------- K5: out_proj (weight-streaming)
__global__ void k_oproj(const float* __restrict__ ynorm, const float* __restrict__ opw,
                        float* __restrict__ oh) {
  int oc = blockIdx.x;            // 0..1 : o = oc*256 + t
  int blc = blockIdx.y;           // 0..31: bl = blc*4 + r
  int t = threadIdx.x;
  __shared__ float yr[4][DINNER]; // 16 KB
  for (int idx = t; idx < 4*DINNER; idx += 256) {
    int r = idx >> 10, k = idx & 1023;
    yr[r][k] = ynorm[(size_t)(blc*4 + r)*DINNER + k];
  }
  __syncthreads();
  int o = oc*256 + t;
  const float4* wr = (const float4*)(opw + (size_t)o*DINNER);
  float acc[4] = {0,0,0,0};
  for (int k4 = 0; k4 < DINNER/4; ++k4) {
    float4 wv = wr[k4];
    #pragma unroll
    for (int r = 0; r < 4; ++r) acc[r] += dot4(wv, &yr[r][k4*4]);
  }
  #pragma unroll
  for (int r = 0; r < 4; ++r)
    oh[(size_t)(blc*4 + r)*DMODEL + o] = acc[r];
}

// ---------------------------------------------------------------- K6: build M in B-fragment order (bf16)
__global__ void k_mfrag(const float* __restrict__ oh, const float* __restrict__ tow,
                        unsigned short* __restrict__ mfp) {
  int bgc = blockIdx.x;            // 0..15, bg = bgc*8 + r
  int dc  = blockIdx.y;            // 0..3 : d = dc*64 + dl
  int t = threadIdx.x;
  __shared__ float orow[8][DMODEL]; // 16 KB
  for (int idx = t; idx < 8*DMODEL; idx += 256) {
    int r = idx >> 9, m = idx & 511;
    orow[r][m] = oh[(size_t)(bgc*8 + r)*DMODEL + m];
  }
  __syncthreads();
  #pragma unroll
  for (int ii = 0; ii < 2; ++ii) {
    int idx = t + 256*ii;          // 0..511 -> (h, dl)
    int h = idx >> 6, dl = idx & 63;
    int d = dc*64 + dl;
    const float4* wr = (const float4*)(tow + (size_t)d*DMODEL + h*64);
    float acc[8] = {0,0,0,0,0,0,0,0};
    #pragma unroll
    for (int c4 = 0; c4 < 16; ++c4) {
      float4 wv = wr[c4];
      #pragma unroll
      for (int r = 0; r < 8; ++r) acc[r] += dot4(wv, &orow[r][h*64 + c4*4]);
    }
    #pragma unroll
    for (int r = 0; r < 8; ++r) {
      int bg = bgc*8 + r; int b = bg >> 6, g = bg & 63;
      int kk = g >> 5;
      int ln = (d & 15) | (((g & 31) >> 3) << 4);
      int j = g & 7;
      mfp[((((size_t)(b*HEADS_O + h)*2 + kk)*16 + (d >> 4))*64 + ln)*8 + j] = f2bf(acc[r]);
    }
  }
}

// ---------------------------------------------------------------- K7: amplification-1x GEMM, convert-once bf16 A-share
// out[b,n,d] = sum_{h,g} W[b,h,n,g]*M[b,h,g,d] + tob[d]
// 256 blocks x 512 thr (8 waves), 1 block/CU. Block owns b and chunks
// c = base + 128k (16 rows each). Per chunk: wave w loads head-w's two
// k-steps of A (4x float4) to REGISTERS, converts to bf16 ONCE, ds_writes
// ready-to-use MFMA A-fragments (16B/lane) into a 16KB double-buffered LDS
// tile. All waves then consume with ONE ds_read_b128 per (ks, MFMA-pair).
// B (256 cols) in registers: wave w holds ct tiles {2w,2w+1} (128 VGPR).
// W crosses the fabric once (410 MB) + stores (205 MB). Loads for chunk
// n+1 are issued at iteration start, first used (convert) at iteration end
// -> full ~4700cy in-flight window; compiler waits vmcnt(8) there (stores
// stay outstanding); the per-chunk barrier is lgkmcnt(0)+s_barrier only.
__global__ __launch_bounds__(512, 1) void k_out_gemm(const float* __restrict__ W,
                                                     const unsigned short* __restrict__ mf,
                                                     const float* __restrict__ tob,
                                                     float* __restrict__ out) {
  int bx = blockIdx.x;
  int b    = bx >> 7;
  int base = bx & 127;
  int tid = threadIdx.x;
  int wv = tid >> 6, lane = tid & 63;
  int r16 = lane & 15, kg = lane >> 4;

  __shared__ __align__(16) unsigned short lsA[2][16][512];  // [buf][ks][lane*8] bf16 = 32 KB

  // ---- B fragments into registers: wave wv owns ct = 2wv, 2wv+1
  short8v B0[16], B1[16];
  {
    const unsigned short* mfb = mf + (size_t)b*(16*16*512) + lane*8;
    #pragma unroll
    for (int ks = 0; ks < 16; ++ks) {
      B0[ks] = *(const short8v*)(mfb + ((size_t)ks*16 + 2*wv    )*512);
      B1[ks] = *(const short8v*)(mfb + ((size_t)ks*16 + 2*wv + 1)*512);
    }
  }
  float bias0 = tob[wv*32 + r16];
  float bias1 = tob[wv*32 + 16 + r16];

  // stager: wave wv loads head h=wv, both kk halves (ks = 2wv, 2wv+1)
  // src(cc,kk) = W + ((b*8+wv)*NMESH + cc*16 + r16)*64 + kk*32 + kg*8
  const float* wbase = W + ((size_t)(b*HEADS_O + wv)*NMESH + r16)*64 + kg*8;

  float4 s00, s01, s10, s11;
  #define ALOAD(cc) do { \
    const float* p0 = wbase + (size_t)(cc)*1024; \
    s00 = *(const float4*)p0;        s01 = *(const float4*)(p0 + 4); \
    s10 = *(const float4*)(p0 + 32); s11 = *(const float4*)(p0 + 36); \
  } while (0)
  #define AWRITE(pp) do { \
    *(short8v*)&lsA[pp][2*wv    ][lane*8] = pack_bf16(s00, s01); \
    *(short8v*)&lsA[pp][2*wv + 1][lane*8] = pack_bf16(s10, s11); \
  } while (0)

  // ---- prologue: stage chunk `base` into buf 0
  ALOAD(base);
  AWRITE(0);
  asm volatile("s_waitcnt lgkmcnt(0)" ::: "memory");
  __builtin_amdgcn_sched_barrier(0);
  __builtin_amdgcn_s_barrier();
  __builtin_amdgcn_sched_barrier(0);

  int c = base;
  int p = 0;
  for (;;) {
    int cn = c + 128;
    bool more = (cn < NCHUNK);
    if (more) ALOAD(cn);                      // 4 loads, land by iteration end
    __builtin_amdgcn_sched_barrier(0);

    f32x4 acc0 = (f32x4){0.f,0.f,0.f,0.f};
    f32x4 acc1 = (f32x4){0.f,0.f,0.f,0.f};
    #pragma unroll
    for (int ks = 0; ks < 16; ++ks) {
      short8v af = *(const short8v*)&lsA[p][ks][lane*8];
      acc0 = __builtin_amdgcn_mfma_f32_16x16x32_bf16(af, B0[ks], acc0, 0, 0, 0);
      acc1 = __builtin_amdgcn_mfma_f32_16x16x32_bf16(af, B1[ks], acc1, 0, 0, 0);
    }

    // stores: col=lane&15, row=kg*4+r
    int rb = c*16 + kg*4;
    int cg = wv*32 + r16;
    #pragma unroll
    for (int r = 0; r < 4; ++r) {
      out[((size_t)b*NMESH + rb + r)*DOUT + cg]      = acc0[r] + bias0;
      out[((size_t)b*NMESH + rb + r)*DOUT + cg + 16] = acc1[r] + bias1;
    }

    if (!more) break;
    __builtin_amdgcn_sched_barrier(0);
    AWRITE(p ^ 1);                            // convert once, share (waits vmcnt(8))
    asm volatile("s_waitcnt lgkmcnt(0)" ::: "memory");
    __builtin_amdgcn_sched_barrier(0);
    __builtin_amdgcn_s_barrier();
    __builtin_amdgcn_sched_barrier(0);
    p ^= 1;
    c = cn;
  }
  #undef ALOAD
  #undef AWRITE
}

// ----------------------------------------------------------------
extern "C" void kernel_launch(void* const* d_in, const int* in_sizes, int n_in,
                              void* d_out, int out_size, void* d_ws, size_t ws_size,
                              hipStream_t stream) {
  (void)in_sizes; (void)n_in; (void)out_size; (void)ws_size;
  const float* st   = (const float*)d_in[0];
  const float* sw   = (const float*)d_in[1];
  const float* ipw  = (const float*)d_in[2];
  const float* cw   = (const float*)d_in[3];
  const float* cb   = (const float*)d_in[4];
  const float* dtb  = (const float*)d_in[5];
  const float* alog = (const float*)d_in[6];
  const float* fcD  = (const float*)d_in[7];
  const float* Dd   = (const float*)d_in[8];
  const float* nw   = (const float*)d_in[9];
  const float* opw  = (const float*)d_in[10];
  const float* tow  = (const float*)d_in[11];
  const float* tob  = (const float*)d_in[12];
  float* out = (float*)d_out;
  unsigned char* ws = (unsigned char*)d_ws;

  float* zx   = (float*)(ws + 0);            // 2*64*2208*4 = 1130496
  float* conv = (float*)(ws + 1130496);      // 2*64*1152*4 = 589824
  float* dtp  = (float*)(ws + 1720320);      // 4*64*16*4   = 16384
  float* yb   = (float*)(ws + 1736704);      // 4*64*1024*4 = 1048576
  float* ynm  = (float*)(ws + 2785280);      // 2*64*1024*4 = 524288
  float* oh   = (float*)(ws + 3309568);      // 2*64*512*4  = 262144
  unsigned short* mfr = (unsigned short*)(ws + 3571712);  // 524288

  k_inproj  <<<dim3(9, 16), 256, 0, stream>>>(st, ipw, zx);
  k_convdt  <<<592, 256, 0, stream>>>(zx, cw, cb, dtb, conv, dtp);
  k_scan    <<<64,  256, 0, stream>>>(conv, dtp, alog, yb);
  k_norm    <<<128, 256, 0, stream>>>(conv, zx, yb, fcD, Dd, nw, ynm);
  k_oproj   <<<dim3(2, 32), 256, 0, stream>>>(ynm, opw, oh);
  k_mfrag   <<<dim3(16, 4), 256, 0, stream>>>(oh, tow, mfr);
  k_out_gemm<<<256, 512, 0, stream>>>(sw, mfr, tob, out);
}